// Round 13
// baseline (110.892 us; speedup 1.0000x reference)
//
#include <hip/hip_runtime.h>

#define NORIENT 8

// XCD-aware block swizzle: dispatch d -> XCD d%8 (round-robin). Remap so each
// XCD gets a contiguous chunk of logical tiles (halo rows shared in its L2).
__device__ __forceinline__ unsigned xcd_swz(unsigned bid, unsigned nwg) {
    unsigned chunk = nwg >> 3;
    return (nwg & 7u) ? bid : (bid & 7u) * chunk + (bid >> 3);
}

// -------- forward, wave-per-channel: stride-2 5x5 conv, 1 -> 8 ch --------
// (exact R12 version — best fwd so far; weights hoisted to SGPRs per wave)
__global__ void fwd_conv_wave_kernel(const float* __restrict__ in, long in_img_stride,
                                     const float* __restrict__ filt,
                                     float* __restrict__ out,
                                     int H, int W, int OH, int OW, int N) {
    constexpr int SROW = 104;
    __shared__ float tile[67 * SROW];      // 27,872 B

    int nbx = OW >> 5, nby = OH >> 5;
    unsigned sb = xcd_swz(blockIdx.x, gridDim.x);
    int bx = (int)(sb % nbx);
    unsigned t = sb / nbx;
    int by = (int)(t % nby);
    int n = (int)(t / nby);

    const float* __restrict__ ip = in + (long)n * in_img_stride;
    int tid = threadIdx.x;

    int w = __builtin_amdgcn_readfirstlane(tid >> 6);
    const float* __restrict__ F = filt + w * 25;
    float Wt[25];
#pragma unroll
    for (int k = 0; k < 25; ++k) Wt[k] = F[k];

    int gy0 = 64 * by - 2, gx0 = 64 * bx - 4;
#pragma unroll
    for (int k = 0; k < 3; ++k) {
        int e = tid + k * 512;
        if (e < 67 * 18) {
            int row = e / 18, m = e - row * 18;
            int gy = gy0 + row, gx = gx0 + 4 * m;
            bool vl = (gy >= 0) & (gy < H) & (gx >= 0) & (gx <= W - 4);
            float4 val = *(const float4*)(ip + (vl ? ((long)gy * W + gx) : 0));
            float msk = vl ? 1.f : 0.f;
            int off = row * SROW + 4 * m + 4 * (m >> 1);
            *(float4*)&tile[off] = make_float4(val.x * msk, val.y * msk,
                                               val.z * msk, val.w * msk);
        }
    }
    __syncthreads();

    int lane = tid & 63;
    int lx = lane & 7, ly = lane >> 3;

    float acc[4][4];
#pragma unroll
    for (int o = 0; o < 4; ++o)
#pragma unroll
        for (int dx = 0; dx < 4; ++dx) acc[o][dx] = 0.f;

#pragma unroll
    for (int r = 0; r < 11; ++r) {
        int base = (8 * ly + r) * SROW + 12 * lx;
        float4 A = *(const float4*)&tile[base];
        float4 B = *(const float4*)&tile[base + 4];
        float4 C = *(const float4*)&tile[base + 12];
        float4 Dd = *(const float4*)&tile[base + 16];
        float P[16] = {A.x, A.y, A.z, A.w, B.x, B.y, B.z, B.w,
                       C.x, C.y, C.z, C.w, Dd.x, Dd.y, Dd.z, Dd.w};

#pragma unroll
        for (int o = 0; o < 4; ++o) {
            int i = r - 2 * o;
            if (i < 0 || i > 4) continue;
#pragma unroll
            for (int j = 0; j < 5; ++j) {
                float wv = Wt[i * 5 + j];
#pragma unroll
                for (int dx = 0; dx < 4; ++dx)
                    acc[o][dx] = fmaf(P[2 + 2 * dx + j], wv, acc[o][dx]);
            }
        }
    }

    long cs = (long)OH * OW;
    int oy = 32 * by + 4 * ly, ox = 32 * bx + 4 * lx;
    long ob = ((long)n * NORIENT + w) * cs + (long)oy * OW + ox;
#pragma unroll
    for (int o = 0; o < 4; ++o)
        *(float4*)(out + ob + (long)o * OW) =
            make_float4(acc[o][0], acc[o][1], acc[o][2], acc[o][3]);
}

// -------- inverse (LDS-tiled): transposed conv, 8 -> 1 ch, stride 2 --------
// Block = 256 threads = 16x16; output tile 64x64 (32x32 sites; thread = 2x2
// sites = 4x4 outputs). Stage 8 channels x 34 rows x 40 cols (43.5 KB) with
// whole-float4-valid aligned loads (w % 4 == 0), batched prefetch in 2 epochs
// (R9 lesson). Compute: borders pre-zeroed in LDS -> no masks; per channel
// 8 aligned LDS reads + R4-verified accumulation. Per-thread VMEM 96 -> ~11.
__global__ void inv_tconv_lds_kernel(const float* __restrict__ rec, long rec_img_stride,
                                     const float* __restrict__ coef,
                                     const float* __restrict__ filt,
                                     float* __restrict__ out,
                                     int h, int w, int N) {
    constexpr int SROW = 40;           // staged cols per row (floats)
    constexpr int CH = 34 * SROW;      // 1360 floats per channel
    __shared__ float tile[NORIENT * CH];   // 43,520 B

    int nbx = w >> 5, nby = h >> 5;    // site tiles of 32x32
    unsigned sb = xcd_swz(blockIdx.x, gridDim.x);
    int bx = (int)(sb % nbx);
    unsigned tt = sb / nbx;
    int by = (int)(tt % nby);
    int n = (int)(tt / nby);

    int S0 = 32 * by, Q0 = 32 * bx;    // first site row/col of tile
    long cs = (long)h * w;
    const float* __restrict__ rp = rec + (long)n * rec_img_stride;
    const float* __restrict__ cp = coef + (long)n * NORIENT * cs;

    int tid = threadIdx.x;

    // ---- stage: 8ch x 34 rows x 10 float4 = 2720 float4s, two epochs ----
    // staged col 0 maps to global col Q0-4; row 0 maps to site row S0-1.
    {
        float4 v[6]; int o[6]; unsigned msk = 0;
#pragma unroll
        for (int k = 0; k < 6; ++k) {
            int e = tid + 256 * k;
            int ech = e / 340, rem = e - ech * 340;
            int row = rem / 10, m = rem - row * 10;
            int gy = S0 - 1 + row, gx = Q0 - 4 + 4 * m;
            bool vl = (gy >= 0) & (gy < h) & (gx >= 0) & (gx <= w - 4);
            const float* __restrict__ src = ech ? (cp + (long)ech * cs) : rp;
            v[k] = *(const float4*)(src + (vl ? ((long)gy * w + gx) : 0));
            o[k] = ech * CH + row * SROW + 4 * m;
            msk |= (vl ? 1u : 0u) << k;
        }
#pragma unroll
        for (int k = 0; k < 6; ++k) {
            float mm = ((msk >> k) & 1u) ? 1.f : 0.f;
            *(float4*)&tile[o[k]] = make_float4(v[k].x * mm, v[k].y * mm,
                                                v[k].z * mm, v[k].w * mm);
        }
    }
    {
        float4 v[5]; int o[5]; unsigned msk = 0;
#pragma unroll
        for (int k = 0; k < 5; ++k) {
            int e = tid + 256 * (6 + k);
            bool inr = e < 2720;
            int e2 = inr ? e : 0;
            int ech = e2 / 340, rem = e2 - ech * 340;
            int row = rem / 10, m = rem - row * 10;
            int gy = S0 - 1 + row, gx = Q0 - 4 + 4 * m;
            bool vl = inr & (gy >= 0) & (gy < h) & (gx >= 0) & (gx <= w - 4);
            const float* __restrict__ src = ech ? (cp + (long)ech * cs) : rp;
            v[k] = *(const float4*)(src + (vl ? ((long)gy * w + gx) : 0));
            o[k] = inr ? (ech * CH + row * SROW + 4 * m) : -1;
            msk |= (vl ? 1u : 0u) << k;
        }
#pragma unroll
        for (int k = 0; k < 5; ++k) {
            if (o[k] >= 0) {
                float mm = ((msk >> k) & 1u) ? 1.f : 0.f;
                *(float4*)&tile[o[k]] = make_float4(v[k].x * mm, v[k].y * mm,
                                                    v[k].z * mm, v[k].w * mm);
            }
        }
    }
    __syncthreads();

    // ---- compute: thread (sx,sy) -> local sites rows {2sy,2sy+1} cols {2sx,2sx+1} ----
    int sx = tid & 15, sy = tid >> 4;

    float acc[2][2][2][2];  // [sr][sc][dy][dx]
#pragma unroll
    for (int i = 0; i < 2; ++i)
#pragma unroll
        for (int j = 0; j < 2; ++j)
#pragma unroll
            for (int k = 0; k < 2; ++k)
#pragma unroll
                for (int l = 0; l < 2; ++l) acc[i][j][k][l] = 0.f;

#pragma unroll
    for (int c = 0; c < NORIENT; ++c) {
        const float* __restrict__ F = filt + c * 25;   // contiguous -> merged s_loads
        const float* __restrict__ tc = &tile[c * CH];

        // patch rows: site rows 2sy-1 .. 2sy+2 -> LDS rows 2sy .. 2sy+3
        // patch cols: site cols 2sx-1 .. 2sx+2 -> staged cols 2sx+3 .. 2sx+6
        float P[4][4];
#pragma unroll
        for (int r = 0; r < 4; ++r) {
            const float* rowp = tc + (2 * sy + r) * SROW;
            float2 L = *(const float2*)(rowp + 2 * sx + 2);   // cols +2,+3
            float4 Ff = *(const float4*)(rowp + 2 * sx + 4);  // cols +4..+7
            P[r][0] = L.y; P[r][1] = Ff.x; P[r][2] = Ff.y; P[r][3] = Ff.z;
        }

#pragma unroll
        for (int a = 0; a < 3; ++a) {
#pragma unroll
            for (int b = 0; b < 3; ++b) {
                float w00 = F[(4 - 2 * a) * 5 + (4 - 2 * b)];
                float w01 = (b >= 1) ? F[(4 - 2 * a) * 5 + (5 - 2 * b)] : 0.f;
                float w10 = (a >= 1) ? F[(5 - 2 * a) * 5 + (4 - 2 * b)] : 0.f;
                float w11 = (a >= 1 && b >= 1) ? F[(5 - 2 * a) * 5 + (5 - 2 * b)] : 0.f;
#pragma unroll
                for (int sr = 0; sr < 2; ++sr) {
#pragma unroll
                    for (int sc = 0; sc < 2; ++sc) {
                        float pv = P[sr + a][sc + b];
                        acc[sr][sc][0][0] = fmaf(pv, w00, acc[sr][sc][0][0]);
                        if (b >= 1) acc[sr][sc][0][1] = fmaf(pv, w01, acc[sr][sc][0][1]);
                        if (a >= 1) acc[sr][sc][1][0] = fmaf(pv, w10, acc[sr][sc][1][0]);
                        if (a >= 1 && b >= 1)
                                    acc[sr][sc][1][1] = fmaf(pv, w11, acc[sr][sc][1][1]);
                    }
                }
            }
        }
    }

    int OW = w << 1;
    long ob = (long)n * 4 * cs + (long)(2 * S0 + 4 * sy) * OW + (2 * Q0 + 4 * sx);
    *(float4*)(out + ob)          = make_float4(acc[0][0][0][0], acc[0][0][0][1],
                                                acc[0][1][0][0], acc[0][1][0][1]);
    *(float4*)(out + ob + OW)     = make_float4(acc[0][0][1][0], acc[0][0][1][1],
                                                acc[0][1][1][0], acc[0][1][1][1]);
    *(float4*)(out + ob + 2 * OW) = make_float4(acc[1][0][0][0], acc[1][0][0][1],
                                                acc[1][1][0][0], acc[1][1][0][1]);
    *(float4*)(out + ob + 3 * OW) = make_float4(acc[1][0][1][0], acc[1][0][1][1],
                                                acc[1][1][1][0], acc[1][1][1][1]);
}

extern "C" void kernel_launch(void* const* d_in, const int* in_sizes, int n_in,
                              void* d_out, int out_size, void* d_ws, size_t ws_size,
                              hipStream_t stream) {
    const float* x     = (const float*)d_in[0];
    const float* fwd_f = (const float*)d_in[1];
    const float* inv_f = (const float*)d_in[2];
    float* out = (float*)d_out;
    float* ws  = (float*)d_ws;

    const int N = 32;

    // workspace layout (floats) — all offsets multiples of 4 -> 16B aligned
    float* l4 = ws;                  // 32*8*256*256 = 16,777,216
    float* l3 = l4 + 16777216;       // 32*8*128*128 =  4,194,304
    float* l2 = l3 + 4194304;        // 32*8*64*64   =  1,048,576
    float* l1 = l2 + 1048576;        // 32*8*32*32   =    262,144
    float* r1 = l1 + 262144;         // 32*64*64     =    131,072
    float* r2 = r1 + 131072;         // 32*128*128   =    524,288
    float* r3 = r2 + 524288;         // 32*256*256   =  2,097,152

    dim3 blkF(512), blk(256);

    // ---- forward transform: wave-per-channel, grid = N * (OH/32) * (OW/32) ----
    fwd_conv_wave_kernel<<<dim3(32 * 8 * 8), blkF, 0, stream>>>(
        x, 512L * 512, fwd_f, l4, 512, 512, 256, 256, N);
    fwd_conv_wave_kernel<<<dim3(32 * 4 * 4), blkF, 0, stream>>>(
        l4, 8L * 256 * 256, fwd_f, l3, 256, 256, 128, 128, N);
    fwd_conv_wave_kernel<<<dim3(32 * 2 * 2), blkF, 0, stream>>>(
        l3, 8L * 128 * 128, fwd_f, l2, 128, 128, 64, 64, N);
    fwd_conv_wave_kernel<<<dim3(32 * 1 * 1), blkF, 0, stream>>>(
        l2, 8L * 64 * 64, fwd_f, l1, 64, 64, 32, 32, N);

    // ---- inverse transform: LDS-tiled, grid = N * (h/32) * (w/32) ----
    inv_tconv_lds_kernel<<<dim3(32 * 1 * 1), blk, 0, stream>>>(
        l1, 8L * 32 * 32, l1, inv_f, r1, 32, 32, N);
    inv_tconv_lds_kernel<<<dim3(32 * 2 * 2), blk, 0, stream>>>(
        r1, 64L * 64, l2, inv_f, r2, 64, 64, N);
    inv_tconv_lds_kernel<<<dim3(32 * 4 * 4), blk, 0, stream>>>(
        r2, 128L * 128, l3, inv_f, r3, 128, 128, N);
    inv_tconv_lds_kernel<<<dim3(32 * 8 * 8), blk, 0, stream>>>(
        r3, 256L * 256, l4, inv_f, out, 256, 256, N);
}

// Round 14
// 106.868 us; speedup vs baseline: 1.0377x; 1.0377x over previous
//
#include <hip/hip_runtime.h>

#define NORIENT 8

// XCD-aware block swizzle (bijective when gridDim % 8 == 0; all our grids are).
__device__ __forceinline__ unsigned xcd_swz(unsigned bid, unsigned nwg) {
    unsigned chunk = nwg >> 3;
    return (nwg & 7u) ? bid : (bid & 7u) * chunk + (bid >> 3);
}

// -------- forward, wave-per-channel: stride-2 5x5 conv, 1 -> 8 ch --------
// (exact R12 version — best fwd so far; weights hoisted to SGPRs per wave)
__global__ void fwd_conv_wave_kernel(const float* __restrict__ in, long in_img_stride,
                                     const float* __restrict__ filt,
                                     float* __restrict__ out,
                                     int H, int W, int OH, int OW, int N) {
    constexpr int SROW = 104;
    __shared__ float tile[67 * SROW];      // 27,872 B

    int nbx = OW >> 5, nby = OH >> 5;
    unsigned sb = xcd_swz(blockIdx.x, gridDim.x);
    int bx = (int)(sb % nbx);
    unsigned t = sb / nbx;
    int by = (int)(t % nby);
    int n = (int)(t / nby);

    const float* __restrict__ ip = in + (long)n * in_img_stride;
    int tid = threadIdx.x;

    int w = __builtin_amdgcn_readfirstlane(tid >> 6);
    const float* __restrict__ F = filt + w * 25;
    float Wt[25];
#pragma unroll
    for (int k = 0; k < 25; ++k) Wt[k] = F[k];

    int gy0 = 64 * by - 2, gx0 = 64 * bx - 4;
#pragma unroll
    for (int k = 0; k < 3; ++k) {
        int e = tid + k * 512;
        if (e < 67 * 18) {
            int row = e / 18, m = e - row * 18;
            int gy = gy0 + row, gx = gx0 + 4 * m;
            bool vl = (gy >= 0) & (gy < H) & (gx >= 0) & (gx <= W - 4);
            float4 val = *(const float4*)(ip + (vl ? ((long)gy * W + gx) : 0));
            float msk = vl ? 1.f : 0.f;
            int off = row * SROW + 4 * m + 4 * (m >> 1);
            *(float4*)&tile[off] = make_float4(val.x * msk, val.y * msk,
                                               val.z * msk, val.w * msk);
        }
    }
    __syncthreads();

    int lane = tid & 63;
    int lx = lane & 7, ly = lane >> 3;

    float acc[4][4];
#pragma unroll
    for (int o = 0; o < 4; ++o)
#pragma unroll
        for (int dx = 0; dx < 4; ++dx) acc[o][dx] = 0.f;

#pragma unroll
    for (int r = 0; r < 11; ++r) {
        int base = (8 * ly + r) * SROW + 12 * lx;
        float4 A = *(const float4*)&tile[base];
        float4 B = *(const float4*)&tile[base + 4];
        float4 C = *(const float4*)&tile[base + 12];
        float4 Dd = *(const float4*)&tile[base + 16];
        float P[16] = {A.x, A.y, A.z, A.w, B.x, B.y, B.z, B.w,
                       C.x, C.y, C.z, C.w, Dd.x, Dd.y, Dd.z, Dd.w};

#pragma unroll
        for (int o = 0; o < 4; ++o) {
            int i = r - 2 * o;
            if (i < 0 || i > 4) continue;
#pragma unroll
            for (int j = 0; j < 5; ++j) {
                float wv = Wt[i * 5 + j];
#pragma unroll
                for (int dx = 0; dx < 4; ++dx)
                    acc[o][dx] = fmaf(P[2 + 2 * dx + j], wv, acc[o][dx]);
            }
        }
    }

    long cs = (long)OH * OW;
    int oy = 32 * by + 4 * ly, ox = 32 * bx + 4 * lx;
    long ob = ((long)n * NORIENT + w) * cs + (long)oy * OW + ox;
#pragma unroll
    for (int o = 0; o < 4; ++o)
        *(float4*)(out + ob + (long)o * OW) =
            make_float4(acc[o][0], acc[o][1], acc[o][2], acc[o][3]);
}

// -------- inverse (LDS-tiled v2, small tile): tconv 8 -> 1 ch, stride 2 --------
// R13 lesson: 43.5 KB tile -> 3 blocks/CU (25% occupancy) -> latency-bound.
// v2: site tile 16x32 (output 32x64); stage 8ch x 18 x 40 floats = 23 KB ->
// ~6 blocks/CU. One batched epoch (6 float4 in flight). Thread = 2 adjacent
// sites = 2x4 outputs; per channel 6 LDS reads + 50 FMA. Same verified
// patch/weight mapping as R13 (which passed).
__global__ void inv_tconv_lds_kernel(const float* __restrict__ rec, long rec_img_stride,
                                     const float* __restrict__ coef,
                                     const float* __restrict__ filt,
                                     float* __restrict__ out,
                                     int h, int w, int N) {
    constexpr int SROW = 40;            // staged cols (floats)
    constexpr int CH = 18 * SROW;       // 720 floats per channel
    __shared__ float tile[NORIENT * CH];    // 23,040 B

    int nbx = w >> 5, nby = h >> 4;     // site tiles: 16 rows x 32 cols
    unsigned sb = xcd_swz(blockIdx.x, gridDim.x);
    int bx = (int)(sb % nbx);
    unsigned tt = sb / nbx;
    int by = (int)(tt % nby);
    int n = (int)(tt / nby);

    int S0 = 16 * by, Q0 = 32 * bx;     // first site row/col of tile
    long cs = (long)h * w;
    const float* __restrict__ rp = rec + (long)n * rec_img_stride;
    const float* __restrict__ cp = coef + (long)n * NORIENT * cs;

    int tid = threadIdx.x;

    // ---- stage: 8ch x 18 rows x 10 float4 = 1440 float4s, one epoch ----
    // staged col 0 = global col Q0-4; staged row 0 = site row S0-1.
    {
        float4 v[6]; int o[6]; unsigned msk = 0;
#pragma unroll
        for (int k = 0; k < 6; ++k) {
            int e = tid + 256 * k;
            bool inr = e < 1440;
            int e2 = inr ? e : 0;
            int ech = e2 / 180, rem = e2 - ech * 180;
            int row = rem / 10, m = rem - row * 10;
            int gy = S0 - 1 + row, gx = Q0 - 4 + 4 * m;
            bool vl = inr & (gy >= 0) & (gy < h) & (gx >= 0) & (gx <= w - 4);
            const float* __restrict__ src = ech ? (cp + (long)ech * cs) : rp;
            v[k] = *(const float4*)(src + (vl ? ((long)gy * w + gx) : 0));
            o[k] = inr ? (ech * CH + row * SROW + 4 * m) : -1;
            msk |= (vl ? 1u : 0u) << k;
        }
#pragma unroll
        for (int k = 0; k < 6; ++k) {
            if (o[k] >= 0) {
                float mm = ((msk >> k) & 1u) ? 1.f : 0.f;
                *(float4*)&tile[o[k]] = make_float4(v[k].x * mm, v[k].y * mm,
                                                    v[k].z * mm, v[k].w * mm);
            }
        }
    }
    __syncthreads();

    // ---- compute: thread (sx,sy) -> sites (S0+sy, Q0+2sx) and (.., Q0+2sx+1) ----
    int sx = tid & 15, sy = tid >> 4;   // sy in 0..15

    float acc[2][2][2];  // [sc][dy][dx]
#pragma unroll
    for (int i = 0; i < 2; ++i)
#pragma unroll
        for (int j = 0; j < 2; ++j) {
            acc[i][j][0] = 0.f;
            acc[i][j][1] = 0.f;
        }

#pragma unroll
    for (int c = 0; c < NORIENT; ++c) {
        const float* __restrict__ F = filt + c * 25;   // contiguous -> merged s_loads
        const float* __restrict__ tc = &tile[c * CH];

        // patch rows: site rows sy-1..sy+1 -> LDS rows sy..sy+2
        // patch cols: site cols 2sx-1..2sx+2 -> staged cols 2sx+3..2sx+6
        float P[3][4];
#pragma unroll
        for (int r = 0; r < 3; ++r) {
            const float* rowp = tc + (sy + r) * SROW;
            float2 L = *(const float2*)(rowp + 2 * sx + 2);   // .y = col 2sx+3
            float4 Ff = *(const float4*)(rowp + 2 * sx + 4);  // cols 2sx+4..7
            P[r][0] = L.y; P[r][1] = Ff.x; P[r][2] = Ff.y; P[r][3] = Ff.z;
        }

#pragma unroll
        for (int a = 0; a < 3; ++a) {
#pragma unroll
            for (int b = 0; b < 3; ++b) {
                float w00 = F[(4 - 2 * a) * 5 + (4 - 2 * b)];
                float w01 = (b >= 1) ? F[(4 - 2 * a) * 5 + (5 - 2 * b)] : 0.f;
                float w10 = (a >= 1) ? F[(5 - 2 * a) * 5 + (4 - 2 * b)] : 0.f;
                float w11 = (a >= 1 && b >= 1) ? F[(5 - 2 * a) * 5 + (5 - 2 * b)] : 0.f;
#pragma unroll
                for (int sc = 0; sc < 2; ++sc) {
                    float pv = P[a][sc + b];
                    acc[sc][0][0] = fmaf(pv, w00, acc[sc][0][0]);
                    if (b >= 1) acc[sc][0][1] = fmaf(pv, w01, acc[sc][0][1]);
                    if (a >= 1) acc[sc][1][0] = fmaf(pv, w10, acc[sc][1][0]);
                    if (a >= 1 && b >= 1)
                                acc[sc][1][1] = fmaf(pv, w11, acc[sc][1][1]);
                }
            }
        }
    }

    int OW = w << 1;
    long ob = (long)n * 4 * cs + (long)(2 * S0 + 2 * sy) * OW + (2 * Q0 + 4 * sx);
    *(float4*)(out + ob)      = make_float4(acc[0][0][0], acc[0][0][1],
                                            acc[1][0][0], acc[1][0][1]);
    *(float4*)(out + ob + OW) = make_float4(acc[0][1][0], acc[0][1][1],
                                            acc[1][1][0], acc[1][1][1]);
}

extern "C" void kernel_launch(void* const* d_in, const int* in_sizes, int n_in,
                              void* d_out, int out_size, void* d_ws, size_t ws_size,
                              hipStream_t stream) {
    const float* x     = (const float*)d_in[0];
    const float* fwd_f = (const float*)d_in[1];
    const float* inv_f = (const float*)d_in[2];
    float* out = (float*)d_out;
    float* ws  = (float*)d_ws;

    const int N = 32;

    // workspace layout (floats) — all offsets multiples of 4 -> 16B aligned
    float* l4 = ws;                  // 32*8*256*256 = 16,777,216
    float* l3 = l4 + 16777216;       // 32*8*128*128 =  4,194,304
    float* l2 = l3 + 4194304;        // 32*8*64*64   =  1,048,576
    float* l1 = l2 + 1048576;        // 32*8*32*32   =    262,144
    float* r1 = l1 + 262144;         // 32*64*64     =    131,072
    float* r2 = r1 + 131072;         // 32*128*128   =    524,288
    float* r3 = r2 + 524288;         // 32*256*256   =  2,097,152

    dim3 blkF(512), blk(256);

    // ---- forward transform: wave-per-channel, grid = N * (OH/32) * (OW/32) ----
    fwd_conv_wave_kernel<<<dim3(32 * 8 * 8), blkF, 0, stream>>>(
        x, 512L * 512, fwd_f, l4, 512, 512, 256, 256, N);
    fwd_conv_wave_kernel<<<dim3(32 * 4 * 4), blkF, 0, stream>>>(
        l4, 8L * 256 * 256, fwd_f, l3, 256, 256, 128, 128, N);
    fwd_conv_wave_kernel<<<dim3(32 * 2 * 2), blkF, 0, stream>>>(
        l3, 8L * 128 * 128, fwd_f, l2, 128, 128, 64, 64, N);
    fwd_conv_wave_kernel<<<dim3(32 * 1 * 1), blkF, 0, stream>>>(
        l2, 8L * 64 * 64, fwd_f, l1, 64, 64, 32, 32, N);

    // ---- inverse transform: LDS-tiled v2, grid = N * (h/16) * (w/32) ----
    inv_tconv_lds_kernel<<<dim3(32 * 2 * 1), blk, 0, stream>>>(
        l1, 8L * 32 * 32, l1, inv_f, r1, 32, 32, N);
    inv_tconv_lds_kernel<<<dim3(32 * 4 * 2), blk, 0, stream>>>(
        r1, 64L * 64, l2, inv_f, r2, 64, 64, N);
    inv_tconv_lds_kernel<<<dim3(32 * 8 * 4), blk, 0, stream>>>(
        r2, 128L * 128, l3, inv_f, r3, 128, 128, N);
    inv_tconv_lds_kernel<<<dim3(32 * 16 * 8), blk, 0, stream>>>(
        r3, 256L * 256, l4, inv_f, out, 256, 256, N);
}

// Round 15
// 98.433 us; speedup vs baseline: 1.1266x; 1.0857x over previous
//
#include <hip/hip_runtime.h>

#define NORIENT 8

// XCD-aware block swizzle (bijective when gridDim % 8 == 0; all our grids are).
__device__ __forceinline__ unsigned xcd_swz(unsigned bid, unsigned nwg) {
    unsigned chunk = nwg >> 3;
    return (nwg & 7u) ? bid : (bid & 7u) * chunk + (bid >> 3);
}

// -------- forward, wave-per-channel: stride-2 5x5 conv, 1 -> 8 ch --------
// (exact R12 version — best fwd so far; weights hoisted to SGPRs per wave)
__global__ void fwd_conv_wave_kernel(const float* __restrict__ in, long in_img_stride,
                                     const float* __restrict__ filt,
                                     float* __restrict__ out,
                                     int H, int W, int OH, int OW, int N) {
    constexpr int SROW = 104;
    __shared__ float tile[67 * SROW];      // 27,872 B

    int nbx = OW >> 5, nby = OH >> 5;
    unsigned sb = xcd_swz(blockIdx.x, gridDim.x);
    int bx = (int)(sb % nbx);
    unsigned t = sb / nbx;
    int by = (int)(t % nby);
    int n = (int)(t / nby);

    const float* __restrict__ ip = in + (long)n * in_img_stride;
    int tid = threadIdx.x;

    int w = __builtin_amdgcn_readfirstlane(tid >> 6);
    const float* __restrict__ F = filt + w * 25;
    float Wt[25];
#pragma unroll
    for (int k = 0; k < 25; ++k) Wt[k] = F[k];

    int gy0 = 64 * by - 2, gx0 = 64 * bx - 4;
#pragma unroll
    for (int k = 0; k < 3; ++k) {
        int e = tid + k * 512;
        if (e < 67 * 18) {
            int row = e / 18, m = e - row * 18;
            int gy = gy0 + row, gx = gx0 + 4 * m;
            bool vl = (gy >= 0) & (gy < H) & (gx >= 0) & (gx <= W - 4);
            float4 val = *(const float4*)(ip + (vl ? ((long)gy * W + gx) : 0));
            float msk = vl ? 1.f : 0.f;
            int off = row * SROW + 4 * m + 4 * (m >> 1);
            *(float4*)&tile[off] = make_float4(val.x * msk, val.y * msk,
                                               val.z * msk, val.w * msk);
        }
    }
    __syncthreads();

    int lane = tid & 63;
    int lx = lane & 7, ly = lane >> 3;

    float acc[4][4];
#pragma unroll
    for (int o = 0; o < 4; ++o)
#pragma unroll
        for (int dx = 0; dx < 4; ++dx) acc[o][dx] = 0.f;

#pragma unroll
    for (int r = 0; r < 11; ++r) {
        int base = (8 * ly + r) * SROW + 12 * lx;
        float4 A = *(const float4*)&tile[base];
        float4 B = *(const float4*)&tile[base + 4];
        float4 C = *(const float4*)&tile[base + 12];
        float4 Dd = *(const float4*)&tile[base + 16];
        float P[16] = {A.x, A.y, A.z, A.w, B.x, B.y, B.z, B.w,
                       C.x, C.y, C.z, C.w, Dd.x, Dd.y, Dd.z, Dd.w};

#pragma unroll
        for (int o = 0; o < 4; ++o) {
            int i = r - 2 * o;
            if (i < 0 || i > 4) continue;
#pragma unroll
            for (int j = 0; j < 5; ++j) {
                float wv = Wt[i * 5 + j];
#pragma unroll
                for (int dx = 0; dx < 4; ++dx)
                    acc[o][dx] = fmaf(P[2 + 2 * dx + j], wv, acc[o][dx]);
            }
        }
    }

    long cs = (long)OH * OW;
    int oy = 32 * by + 4 * ly, ox = 32 * bx + 4 * lx;
    long ob = ((long)n * NORIENT + w) * cs + (long)oy * OW + ox;
#pragma unroll
    for (int o = 0; o < 4; ++o)
        *(float4*)(out + ob + (long)o * OW) =
            make_float4(acc[o][0], acc[o][1], acc[o][2], acc[o][3]);
}

// -------- inverse, channel-split: tconv 8 -> 1 ch, stride 2 --------
// Block = 512 threads; tid and tid+256 own the SAME 2x2-site output block:
// half 0 accumulates rec + ch1-3, half 1 ch4-7 (R4-verified per-channel code).
// Serialized load epochs per thread: 8 -> 4; TLP doubled. Combine via LDS
// (half1 writes acc[16] as 4x float4, 80B row stride -> conflict-free), half0
// adds + stores. No early returns (grids exact); half-branch is wave-uniform.
__global__ void inv_tconv_split_kernel(const float* __restrict__ rec, long rec_img_stride,
                                       const float* __restrict__ coef,
                                       const float* __restrict__ filt,
                                       float* __restrict__ out,
                                       int h, int w, int N) {
    __shared__ float red[256 * 20];        // 20,480 B

    int h2 = h >> 1, w2 = w >> 1;
    unsigned sb = xcd_swz(blockIdx.x, gridDim.x);
    int tid = threadIdx.x;
    int idx256 = tid & 255;
    int half = tid >> 8;

    long idx = (long)sb * 256 + idx256;
    int b0 = (int)(idx % w2);
    long t = idx / w2;
    int a0 = (int)(t % h2);
    int n = (int)(t / h2);

    const float* __restrict__ rp = rec + (long)n * rec_img_stride;
    const float* __restrict__ cp = coef + (long)n * (long)NORIENT * h * w;
    long cs = (long)h * w;

    bool fmv = a0 > 0, fpv = a0 < h2 - 1;
    bool um = b0 > 0, up = b0 < w2 - 1;
    float fm = fmv ? 1.f : 0.f, fp_ = fpv ? 1.f : 0.f;
    int r0 = (fmv ? 2 * a0 - 1 : 0) * w;
    int r1 = (2 * a0) * w;
    int r2 = (2 * a0 + 1) * w;
    int r3 = (fpv ? 2 * a0 + 2 : 2 * a0 + 1) * w;
    int cL = um ? 2 * b0 - 2 : 0;
    int cM = 2 * b0;
    int cR = up ? 2 * b0 + 2 : 0;

    float acc[2][2][2][2];  // [sr][sc][dy][dx]
#pragma unroll
    for (int i = 0; i < 2; ++i)
#pragma unroll
        for (int j = 0; j < 2; ++j)
#pragma unroll
            for (int k = 0; k < 2; ++k)
#pragma unroll
                for (int l = 0; l < 2; ++l) acc[i][j][k][l] = 0.f;

    auto do_channel = [&](const float* __restrict__ src, const float* __restrict__ F) {
        float P[4][4];
        const int ro[4] = {r0, r1, r2, r3};
        const float rm[4] = {fm, 1.f, 1.f, fp_};
#pragma unroll
        for (int r = 0; r < 4; ++r) {
            const float* base = src + ro[r];
            float2 L = *(const float2*)(base + cL);
            float2 M = *(const float2*)(base + cM);
            float2 R = *(const float2*)(base + cR);
            float mask = rm[r];
            P[r][0] = (um ? L.y : 0.f) * mask;
            P[r][1] = M.x * mask;
            P[r][2] = M.y * mask;
            P[r][3] = (up ? R.x : 0.f) * mask;
        }
#pragma unroll
        for (int a = 0; a < 3; ++a) {
#pragma unroll
            for (int b = 0; b < 3; ++b) {
                float w00 = F[(4 - 2 * a) * 5 + (4 - 2 * b)];
                float w01 = (b >= 1) ? F[(4 - 2 * a) * 5 + (5 - 2 * b)] : 0.f;
                float w10 = (a >= 1) ? F[(5 - 2 * a) * 5 + (4 - 2 * b)] : 0.f;
                float w11 = (a >= 1 && b >= 1) ? F[(5 - 2 * a) * 5 + (5 - 2 * b)] : 0.f;
#pragma unroll
                for (int sr = 0; sr < 2; ++sr) {
#pragma unroll
                    for (int sc = 0; sc < 2; ++sc) {
                        float pv = P[sr + a][sc + b];
                        acc[sr][sc][0][0] = fmaf(pv, w00, acc[sr][sc][0][0]);
                        if (b >= 1) acc[sr][sc][0][1] = fmaf(pv, w01, acc[sr][sc][0][1]);
                        if (a >= 1) acc[sr][sc][1][0] = fmaf(pv, w10, acc[sr][sc][1][0]);
                        if (a >= 1 && b >= 1)
                                    acc[sr][sc][1][1] = fmaf(pv, w11, acc[sr][sc][1][1]);
                    }
                }
            }
        }
    };

    if (half == 0) {
        do_channel(rp, filt);
#pragma unroll
        for (int c = 1; c < 4; ++c)
            do_channel(cp + (long)c * cs, filt + c * 25);
    } else {
#pragma unroll
        for (int c = 4; c < 8; ++c)
            do_channel(cp + (long)c * cs, filt + c * 25);
    }

    const float* a = &acc[0][0][0][0];
    if (half == 1) {
#pragma unroll
        for (int k = 0; k < 4; ++k)
            *(float4*)&red[idx256 * 20 + 4 * k] =
                make_float4(a[4 * k], a[4 * k + 1], a[4 * k + 2], a[4 * k + 3]);
    }
    __syncthreads();
    if (half == 0) {
        float* aw = &acc[0][0][0][0];
#pragma unroll
        for (int k = 0; k < 4; ++k) {
            float4 r = *(const float4*)&red[idx256 * 20 + 4 * k];
            aw[4 * k]     += r.x;
            aw[4 * k + 1] += r.y;
            aw[4 * k + 2] += r.z;
            aw[4 * k + 3] += r.w;
        }

        int OW = w << 1;
        long ob = (long)n * 4 * cs + (long)(4 * a0) * OW + 4 * b0;
        *(float4*)(out + ob)          = make_float4(acc[0][0][0][0], acc[0][0][0][1],
                                                    acc[0][1][0][0], acc[0][1][0][1]);
        *(float4*)(out + ob + OW)     = make_float4(acc[0][0][1][0], acc[0][0][1][1],
                                                    acc[0][1][1][0], acc[0][1][1][1]);
        *(float4*)(out + ob + 2 * OW) = make_float4(acc[1][0][0][0], acc[1][0][0][1],
                                                    acc[1][1][0][0], acc[1][1][0][1]);
        *(float4*)(out + ob + 3 * OW) = make_float4(acc[1][0][1][0], acc[1][0][1][1],
                                                    acc[1][1][1][0], acc[1][1][1][1]);
    }
}

extern "C" void kernel_launch(void* const* d_in, const int* in_sizes, int n_in,
                              void* d_out, int out_size, void* d_ws, size_t ws_size,
                              hipStream_t stream) {
    const float* x     = (const float*)d_in[0];
    const float* fwd_f = (const float*)d_in[1];
    const float* inv_f = (const float*)d_in[2];
    float* out = (float*)d_out;
    float* ws  = (float*)d_ws;

    const int N = 32;

    // workspace layout (floats) — all offsets multiples of 4 -> 16B aligned
    float* l4 = ws;                  // 32*8*256*256 = 16,777,216
    float* l3 = l4 + 16777216;       // 32*8*128*128 =  4,194,304
    float* l2 = l3 + 4194304;        // 32*8*64*64   =  1,048,576
    float* l1 = l2 + 1048576;        // 32*8*32*32   =    262,144
    float* r1 = l1 + 262144;         // 32*64*64     =    131,072
    float* r2 = r1 + 131072;         // 32*128*128   =    524,288
    float* r3 = r2 + 524288;         // 32*256*256   =  2,097,152

    dim3 blkF(512), blkI(512);

    // ---- forward transform: wave-per-channel, grid = N * (OH/32) * (OW/32) ----
    fwd_conv_wave_kernel<<<dim3(32 * 8 * 8), blkF, 0, stream>>>(
        x, 512L * 512, fwd_f, l4, 512, 512, 256, 256, N);
    fwd_conv_wave_kernel<<<dim3(32 * 4 * 4), blkF, 0, stream>>>(
        l4, 8L * 256 * 256, fwd_f, l3, 256, 256, 128, 128, N);
    fwd_conv_wave_kernel<<<dim3(32 * 2 * 2), blkF, 0, stream>>>(
        l3, 8L * 128 * 128, fwd_f, l2, 128, 128, 64, 64, N);
    fwd_conv_wave_kernel<<<dim3(32 * 1 * 1), blkF, 0, stream>>>(
        l2, 8L * 64 * 64, fwd_f, l1, 64, 64, 32, 32, N);

    // ---- inverse transform: channel-split, grid = N*h2*w2/256 blocks ----
    inv_tconv_split_kernel<<<dim3(32), blkI, 0, stream>>>(
        l1, 8L * 32 * 32, l1, inv_f, r1, 32, 32, N);
    inv_tconv_split_kernel<<<dim3(128), blkI, 0, stream>>>(
        r1, 64L * 64, l2, inv_f, r2, 64, 64, N);
    inv_tconv_split_kernel<<<dim3(512), blkI, 0, stream>>>(
        r2, 128L * 128, l3, inv_f, r3, 128, 128, N);
    inv_tconv_split_kernel<<<dim3(2048), blkI, 0, stream>>>(
        r3, 256L * 256, l4, inv_f, out, 256, 256, N);
}